// Round 1
// baseline (3262.704 us; speedup 1.0000x reference)
//
#include <hip/hip_runtime.h>
#include <hip/hip_bf16.h>

#define N_NODES 20000
#define N_EDGES 640000
#define HID 256
#define INDIM 128

// ---------- ws layout (bytes) ----------
// [0, 10'240'000)              h as bf16: 20000*256*2
// [10'240'000, 30'720'000)     agg as f32: 20000*256*4
// [30'720'000, 30'721'024)     colsum: 256*4
#define WS_H_OFF   0
#define WS_AGG_OFF 10240000
#define WS_CS_OFF  (10240000 + 20480000)

__device__ inline unsigned short f2bf(float v) {
    union { float f; unsigned int u; } c; c.f = v;
    unsigned int lsb = (c.u >> 16) & 1u;
    c.u += 0x7fffu + lsb;                 // round-to-nearest-even
    return (unsigned short)(c.u >> 16);
}
__device__ inline float bf2f(unsigned short u) {
    union { float f; unsigned int u; } c; c.u = ((unsigned int)u) << 16;
    return c.f;
}

// ---------------------------------------------------------------------------
// Kernel 1: h = relu(x @ emb_W.T + emb_b), stored bf16.  32 nodes per block,
// thread j owns output column j for all 32 nodes. x tile staged in LDS
// (broadcast reads), W rows read per-thread from global (L2-resident, 131KB).
// ---------------------------------------------------------------------------
__global__ __launch_bounds__(256) void k_embed(const float* __restrict__ x,
                                               const float* __restrict__ W,
                                               const float* __restrict__ b,
                                               unsigned short* __restrict__ hbf)
{
    __shared__ float xs[32 * INDIM];   // 16 KB
    const int tid = threadIdx.x;
    const int n0  = blockIdx.x * 32;

    // cooperative load of 32x128 f32 = 1024 float4
    {
        const float4* xg = (const float4*)(x + (size_t)n0 * INDIM);
        float4* xs4 = (float4*)xs;
#pragma unroll
        for (int i = 0; i < 4; ++i) xs4[tid + i * 256] = xg[tid + i * 256];
    }
    __syncthreads();

    const int j = tid;                          // output column
    const float4* wr = (const float4*)(W + (size_t)j * INDIM);
    const float bias = b[j];

    float acc[32];
#pragma unroll
    for (int n = 0; n < 32; ++n) acc[n] = bias;

#pragma unroll
    for (int kc = 0; kc < 2; ++kc) {            // K chunks of 64 floats
        float4 w[16];
#pragma unroll
        for (int q = 0; q < 16; ++q) w[q] = wr[kc * 16 + q];
#pragma unroll
        for (int n = 0; n < 32; ++n) {
            float s = 0.f;
#pragma unroll
            for (int q = 0; q < 16; ++q) {
                float4 xv = *((const float4*)(xs + n * INDIM + kc * 64 + q * 4));
                s += xv.x * w[q].x + xv.y * w[q].y + xv.z * w[q].z + xv.w * w[q].w;
            }
            acc[n] += s;
        }
    }

#pragma unroll
    for (int n = 0; n < 32; ++n) {
        float v = acc[n] > 0.f ? acc[n] : 0.f;
        hbf[(size_t)(n0 + n) * HID + j] = f2bf(v);
    }
}

// ---------------------------------------------------------------------------
// Kernel 2: agg[row[e]] += h[col[e]].  One wave (64 lanes) per edge, 4 f32
// per lane: bf16x4 gather + 4 f32 hardware atomics.
// ---------------------------------------------------------------------------
__global__ __launch_bounds__(256) void k_scatter(const int* __restrict__ ei,
                                                 const unsigned short* __restrict__ hbf,
                                                 float* __restrict__ agg)
{
    const int gtid = blockIdx.x * 256 + threadIdx.x;
    const int e    = gtid >> 6;
    const int lane = threadIdx.x & 63;
    if (e >= N_EDGES) return;

    const int dst = ei[e];             // row
    const int src = ei[N_EDGES + e];   // col

    ushort4 hv = ((const ushort4*)hbf)[(size_t)src * 64 + lane];
    float4 f;
    f.x = bf2f(hv.x); f.y = bf2f(hv.y); f.z = bf2f(hv.z); f.w = bf2f(hv.w);

    float* a = agg + (size_t)dst * HID + lane * 4;
    unsafeAtomicAdd(a + 0, f.x);
    unsafeAtomicAdd(a + 1, f.y);
    unsafeAtomicAdd(a + 2, f.z);
    unsafeAtomicAdd(a + 3, f.w);
}

// ---------------------------------------------------------------------------
// Kernel 3: h2 = relu(agg @ msg_W.T + msg_b); column-sum into colsum.
// h2 never materialized.  32 nodes per block, thread j owns column j.
// ---------------------------------------------------------------------------
__global__ __launch_bounds__(256) void k_msg(const float* __restrict__ agg,
                                             const float* __restrict__ W,
                                             const float* __restrict__ b,
                                             float* __restrict__ colsum)
{
    __shared__ float xs[32 * HID];     // 32 KB
    const int tid = threadIdx.x;
    const int n0  = blockIdx.x * 32;

    {
        const float4* xg = (const float4*)(agg + (size_t)n0 * HID);
        float4* xs4 = (float4*)xs;
#pragma unroll
        for (int i = 0; i < 8; ++i) xs4[tid + i * 256] = xg[tid + i * 256];
    }
    __syncthreads();

    const int j = tid;
    const float4* wr = (const float4*)(W + (size_t)j * HID);
    const float bias = b[j];

    float acc[32];
#pragma unroll
    for (int n = 0; n < 32; ++n) acc[n] = bias;

#pragma unroll
    for (int kc = 0; kc < 4; ++kc) {            // K chunks of 64 floats
        float4 w[16];
#pragma unroll
        for (int q = 0; q < 16; ++q) w[q] = wr[kc * 16 + q];
#pragma unroll
        for (int n = 0; n < 32; ++n) {
            float s = 0.f;
#pragma unroll
            for (int q = 0; q < 16; ++q) {
                float4 xv = *((const float4*)(xs + n * HID + kc * 64 + q * 4));
                s += xv.x * w[q].x + xv.y * w[q].y + xv.z * w[q].z + xv.w * w[q].w;
            }
            acc[n] += s;
        }
    }

    float part = 0.f;
#pragma unroll
    for (int n = 0; n < 32; ++n) {
        float v = acc[n] > 0.f ? acc[n] : 0.f;
        part += v;
    }
    unsafeAtomicAdd(&colsum[j], part);
}

// ---------------------------------------------------------------------------
// Kernel 4: hmean = colsum/N; w0 = hmean@W0.T + b0 ; w1 = hmean@W1.T + b1.
// 10240 outputs, one thread each.
// ---------------------------------------------------------------------------
__global__ __launch_bounds__(256) void k_out(const float* __restrict__ colsum,
                                             const float* __restrict__ W0,
                                             const float* __restrict__ b0,
                                             const float* __restrict__ W1,
                                             const float* __restrict__ b1,
                                             float* __restrict__ out)
{
    __shared__ float hm[HID];
    const int tid = threadIdx.x;
    hm[tid] = colsum[tid] * (1.0f / (float)N_NODES);
    __syncthreads();

    const int o = blockIdx.x * 256 + tid;
    const float* Wr;
    float bias;
    if (o < 8192) { Wr = W0 + (size_t)o * HID; bias = b0[o]; }
    else          { int o1 = o - 8192; Wr = W1 + (size_t)o1 * HID; bias = b1[o1]; }

    float s = bias;
    const float4* w4 = (const float4*)Wr;
    const float4* h4 = (const float4*)hm;
#pragma unroll
    for (int q = 0; q < 64; ++q) {
        float4 wv = w4[q];
        float4 hv = h4[q];
        s += wv.x * hv.x + wv.y * hv.y + wv.z * hv.z + wv.w * hv.w;
    }
    out[o] = s;
}

// ---------------------------------------------------------------------------
extern "C" void kernel_launch(void* const* d_in, const int* in_sizes, int n_in,
                              void* d_out, int out_size, void* d_ws, size_t ws_size,
                              hipStream_t stream)
{
    const float* x     = (const float*)d_in[0];
    const int*   ei    = (const int*)d_in[1];
    const float* emb_W = (const float*)d_in[2];
    const float* emb_b = (const float*)d_in[3];
    const float* msg_W = (const float*)d_in[4];
    const float* msg_b = (const float*)d_in[5];
    const float* W0    = (const float*)d_in[6];
    const float* b0    = (const float*)d_in[7];
    const float* W1    = (const float*)d_in[8];
    const float* b1    = (const float*)d_in[9];
    float* out = (float*)d_out;

    char* ws = (char*)d_ws;
    unsigned short* hbf = (unsigned short*)(ws + WS_H_OFF);
    float* agg    = (float*)(ws + WS_AGG_OFF);
    float* colsum = (float*)(ws + WS_CS_OFF);

    // zero agg + colsum (contiguous)
    hipMemsetAsync(agg, 0, (size_t)N_NODES * HID * 4 + HID * 4, stream);

    k_embed  <<<N_NODES / 32, 256, 0, stream>>>(x, emb_W, emb_b, hbf);
    k_scatter<<<N_EDGES / 4,  256, 0, stream>>>(ei, hbf, agg);
    k_msg    <<<N_NODES / 32, 256, 0, stream>>>(agg, msg_W, msg_b, colsum);
    k_out    <<<(8192 + 2048) / 256, 256, 0, stream>>>(colsum, W0, b0, W1, b1, out);
}

// Round 2
// 1266.988 us; speedup vs baseline: 2.5752x; 2.5752x over previous
//
#include <hip/hip_runtime.h>
#include <hip/hip_bf16.h>

#define N_NODES 20000
#define N_EDGES 640000
#define HID 256
#define INDIM 128

// ---------- ws layout (bytes) ----------
#define WS_H_OFF   0u           // h bf16: 20000*256*2 = 10,240,000
#define WS_AGG_OFF 10240000u    // agg f32: 20000*256*4 = 20,480,000
#define WS_CS_OFF  30720000u    // colsum: 256*4 = 1024
#define WS_DEG_OFF 30721024u    // deg: 20000*4 = 80,000
#define WS_ROW_OFF 30801024u    // rowstart: 20001*4 = 80,004
#define WS_CUR_OFF 30881028u    // cursor: 20000*4 = 80,000
#define WS_SRC_OFF 30961028u    // srcs: 640000*4 = 2,560,000
#define WS_NEEDED  33521028u

__device__ inline unsigned short f2bf(float v) {
    union { float f; unsigned int u; } c; c.f = v;
    unsigned int lsb = (c.u >> 16) & 1u;
    c.u += 0x7fffu + lsb;                 // round-to-nearest-even
    return (unsigned short)(c.u >> 16);
}
__device__ inline float bf2f(unsigned short u) {
    union { float f; unsigned int u; } c; c.u = ((unsigned int)u) << 16;
    return c.f;
}

// ---------------------------------------------------------------------------
// Kernel 1: h = relu(x @ emb_W.T + emb_b), stored bf16.
// ---------------------------------------------------------------------------
__global__ __launch_bounds__(256) void k_embed(const float* __restrict__ x,
                                               const float* __restrict__ W,
                                               const float* __restrict__ b,
                                               unsigned short* __restrict__ hbf)
{
    __shared__ float xs[32 * INDIM];   // 16 KB
    const int tid = threadIdx.x;
    const int n0  = blockIdx.x * 32;

    {
        const float4* xg = (const float4*)(x + (size_t)n0 * INDIM);
        float4* xs4 = (float4*)xs;
#pragma unroll
        for (int i = 0; i < 4; ++i) xs4[tid + i * 256] = xg[tid + i * 256];
    }
    __syncthreads();

    const int j = tid;
    const float4* wr = (const float4*)(W + (size_t)j * INDIM);
    const float bias = b[j];

    float acc[32];
#pragma unroll
    for (int n = 0; n < 32; ++n) acc[n] = bias;

#pragma unroll
    for (int kc = 0; kc < 2; ++kc) {
        float4 w[16];
#pragma unroll
        for (int q = 0; q < 16; ++q) w[q] = wr[kc * 16 + q];
#pragma unroll
        for (int n = 0; n < 32; ++n) {
            float s = 0.f;
#pragma unroll
            for (int q = 0; q < 16; ++q) {
                float4 xv = *((const float4*)(xs + n * INDIM + kc * 64 + q * 4));
                s += xv.x * w[q].x + xv.y * w[q].y + xv.z * w[q].z + xv.w * w[q].w;
            }
            acc[n] += s;
        }
    }

#pragma unroll
    for (int n = 0; n < 32; ++n) {
        float v = acc[n] > 0.f ? acc[n] : 0.f;
        hbf[(size_t)(n0 + n) * HID + j] = f2bf(v);
    }
}

// ---------------------------------------------------------------------------
// CSR build: count degrees, scan, fill src lists.
// ---------------------------------------------------------------------------
__global__ __launch_bounds__(256) void k_count(const int* __restrict__ ei,
                                               int* __restrict__ deg)
{
    const int e = blockIdx.x * 256 + threadIdx.x;
    if (e >= N_EDGES) return;
    atomicAdd(&deg[ei[e]], 1);
}

__global__ __launch_bounds__(1024) void k_scan(const int* __restrict__ deg,
                                               int* __restrict__ rowstart)
{
    __shared__ int sums[1024];
    const int t = threadIdx.x;
    const int per = 20;                     // 1024*20 = 20480 >= 20000
    const int base = t * per;

    int local[per];
    int s = 0;
#pragma unroll
    for (int i = 0; i < per; ++i) {
        int idx = base + i;
        int v = (idx < N_NODES) ? deg[idx] : 0;
        local[i] = s;
        s += v;
    }
    sums[t] = s;
    __syncthreads();

    for (int off = 1; off < 1024; off <<= 1) {
        int v = 0;
        if (t >= off) v = sums[t - off];
        __syncthreads();
        if (t >= off) sums[t] += v;
        __syncthreads();
    }

    const int pre = (t == 0) ? 0 : sums[t - 1];
#pragma unroll
    for (int i = 0; i < per; ++i) {
        int idx = base + i;
        if (idx < N_NODES) rowstart[idx] = pre + local[i];
    }
    if (t == 1023) rowstart[N_NODES] = sums[1023];
}

__global__ __launch_bounds__(256) void k_fill(const int* __restrict__ ei,
                                              const int* __restrict__ rowstart,
                                              int* __restrict__ cursor,
                                              int* __restrict__ srcs)
{
    const int e = blockIdx.x * 256 + threadIdx.x;
    if (e >= N_EDGES) return;
    const int dst = ei[e];
    const int src = ei[N_EDGES + e];
    const int pos = rowstart[dst] + atomicAdd(&cursor[dst], 1);
    srcs[pos] = src;
}

// ---------------------------------------------------------------------------
// Gather: one wave per dst node; lane holds 4 columns. No f32 atomics.
// ---------------------------------------------------------------------------
__global__ __launch_bounds__(256) void k_gather(const int* __restrict__ rowstart,
                                                const int* __restrict__ srcs,
                                                const unsigned short* __restrict__ hbf,
                                                float* __restrict__ agg)
{
    const int wid  = (blockIdx.x * 256 + threadIdx.x) >> 6;  // node id
    const int lane = threadIdx.x & 63;
    if (wid >= N_NODES) return;

    const int s0 = rowstart[wid];
    const int s1 = rowstart[wid + 1];

    float4 acc = make_float4(0.f, 0.f, 0.f, 0.f);
    const ushort4* h4 = (const ushort4*)hbf;

    int e = s0;
    for (; e + 1 < s1; e += 2) {
        int srcA = srcs[e];
        int srcB = srcs[e + 1];
        ushort4 a = h4[(size_t)srcA * 64 + lane];
        ushort4 bv = h4[(size_t)srcB * 64 + lane];
        acc.x += bf2f(a.x) + bf2f(bv.x);
        acc.y += bf2f(a.y) + bf2f(bv.y);
        acc.z += bf2f(a.z) + bf2f(bv.z);
        acc.w += bf2f(a.w) + bf2f(bv.w);
    }
    if (e < s1) {
        int srcA = srcs[e];
        ushort4 a = h4[(size_t)srcA * 64 + lane];
        acc.x += bf2f(a.x);
        acc.y += bf2f(a.y);
        acc.z += bf2f(a.z);
        acc.w += bf2f(a.w);
    }

    ((float4*)agg)[(size_t)wid * 64 + lane] = acc;
}

// ---------------------------------------------------------------------------
// Fallback scatter (atomic path) if ws too small for CSR.
// ---------------------------------------------------------------------------
__global__ __launch_bounds__(256) void k_scatter(const int* __restrict__ ei,
                                                 const unsigned short* __restrict__ hbf,
                                                 float* __restrict__ agg)
{
    const int gtid = blockIdx.x * 256 + threadIdx.x;
    const int e    = gtid >> 6;
    const int lane = threadIdx.x & 63;
    if (e >= N_EDGES) return;

    const int dst = ei[e];
    const int src = ei[N_EDGES + e];

    ushort4 hv = ((const ushort4*)hbf)[(size_t)src * 64 + lane];
    float* a = agg + (size_t)dst * HID + lane * 4;
    unsafeAtomicAdd(a + 0, bf2f(hv.x));
    unsafeAtomicAdd(a + 1, bf2f(hv.y));
    unsafeAtomicAdd(a + 2, bf2f(hv.z));
    unsafeAtomicAdd(a + 3, bf2f(hv.w));
}

// ---------------------------------------------------------------------------
// Kernel 3: h2 = relu(agg @ msg_W.T + msg_b); column-sum into colsum.
// ---------------------------------------------------------------------------
__global__ __launch_bounds__(256) void k_msg(const float* __restrict__ agg,
                                             const float* __restrict__ W,
                                             const float* __restrict__ b,
                                             float* __restrict__ colsum)
{
    __shared__ float xs[32 * HID];     // 32 KB
    const int tid = threadIdx.x;
    const int n0  = blockIdx.x * 32;

    {
        const float4* xg = (const float4*)(agg + (size_t)n0 * HID);
        float4* xs4 = (float4*)xs;
#pragma unroll
        for (int i = 0; i < 8; ++i) xs4[tid + i * 256] = xg[tid + i * 256];
    }
    __syncthreads();

    const int j = tid;
    const float4* wr = (const float4*)(W + (size_t)j * HID);
    const float bias = b[j];

    float acc[32];
#pragma unroll
    for (int n = 0; n < 32; ++n) acc[n] = bias;

#pragma unroll
    for (int kc = 0; kc < 4; ++kc) {
        float4 w[16];
#pragma unroll
        for (int q = 0; q < 16; ++q) w[q] = wr[kc * 16 + q];
#pragma unroll
        for (int n = 0; n < 32; ++n) {
            float s = 0.f;
#pragma unroll
            for (int q = 0; q < 16; ++q) {
                float4 xv = *((const float4*)(xs + n * HID + kc * 64 + q * 4));
                s += xv.x * w[q].x + xv.y * w[q].y + xv.z * w[q].z + xv.w * w[q].w;
            }
            acc[n] += s;
        }
    }

    float part = 0.f;
#pragma unroll
    for (int n = 0; n < 32; ++n) {
        float v = acc[n] > 0.f ? acc[n] : 0.f;
        part += v;
    }
    unsafeAtomicAdd(&colsum[j], part);
}

// ---------------------------------------------------------------------------
// Kernel 4: output matvecs from hmean.
// ---------------------------------------------------------------------------
__global__ __launch_bounds__(256) void k_out(const float* __restrict__ colsum,
                                             const float* __restrict__ W0,
                                             const float* __restrict__ b0,
                                             const float* __restrict__ W1,
                                             const float* __restrict__ b1,
                                             float* __restrict__ out)
{
    __shared__ float hm[HID];
    const int tid = threadIdx.x;
    hm[tid] = colsum[tid] * (1.0f / (float)N_NODES);
    __syncthreads();

    const int o = blockIdx.x * 256 + tid;
    const float* Wr;
    float bias;
    if (o < 8192) { Wr = W0 + (size_t)o * HID; bias = b0[o]; }
    else          { int o1 = o - 8192; Wr = W1 + (size_t)o1 * HID; bias = b1[o1]; }

    float s = bias;
    const float4* w4 = (const float4*)Wr;
    const float4* h4 = (const float4*)hm;
#pragma unroll
    for (int q = 0; q < 64; ++q) {
        float4 wv = w4[q];
        float4 hv = h4[q];
        s += wv.x * hv.x + wv.y * hv.y + wv.z * hv.z + wv.w * hv.w;
    }
    out[o] = s;
}

// ---------------------------------------------------------------------------
extern "C" void kernel_launch(void* const* d_in, const int* in_sizes, int n_in,
                              void* d_out, int out_size, void* d_ws, size_t ws_size,
                              hipStream_t stream)
{
    const float* x     = (const float*)d_in[0];
    const int*   ei    = (const int*)d_in[1];
    const float* emb_W = (const float*)d_in[2];
    const float* emb_b = (const float*)d_in[3];
    const float* msg_W = (const float*)d_in[4];
    const float* msg_b = (const float*)d_in[5];
    const float* W0    = (const float*)d_in[6];
    const float* b0    = (const float*)d_in[7];
    const float* W1    = (const float*)d_in[8];
    const float* b1    = (const float*)d_in[9];
    float* out = (float*)d_out;

    char* ws = (char*)d_ws;
    unsigned short* hbf = (unsigned short*)(ws + WS_H_OFF);
    float* agg    = (float*)(ws + WS_AGG_OFF);
    float* colsum = (float*)(ws + WS_CS_OFF);

    k_embed<<<N_NODES / 32, 256, 0, stream>>>(x, emb_W, emb_b, hbf);

    if (ws_size >= WS_NEEDED) {
        int* deg      = (int*)(ws + WS_DEG_OFF);
        int* rowstart = (int*)(ws + WS_ROW_OFF);
        int* cursor   = (int*)(ws + WS_CUR_OFF);
        int* srcs     = (int*)(ws + WS_SRC_OFF);

        // zero colsum + deg + rowstart + cursor in one shot
        hipMemsetAsync(ws + WS_CS_OFF, 0, WS_SRC_OFF - WS_CS_OFF, stream);

        k_count <<<(N_EDGES + 255) / 256, 256, 0, stream>>>(ei, deg);
        k_scan  <<<1, 1024, 0, stream>>>(deg, rowstart);
        k_fill  <<<(N_EDGES + 255) / 256, 256, 0, stream>>>(ei, rowstart, cursor, srcs);
        k_gather<<<(N_NODES * 64 + 255) / 256, 256, 0, stream>>>(rowstart, srcs, hbf, agg);
    } else {
        // fallback: atomic scatter
        hipMemsetAsync(agg, 0, (size_t)N_NODES * HID * 4 + HID * 4, stream);
        k_scatter<<<N_EDGES / 4, 256, 0, stream>>>(ei, hbf, agg);
    }

    k_msg<<<N_NODES / 32, 256, 0, stream>>>(agg, msg_W, msg_b, colsum);
    k_out<<<(8192 + 2048) / 256, 256, 0, stream>>>(colsum, W0, b0, W1, b1, out);
}

// Round 3
// 325.541 us; speedup vs baseline: 10.0224x; 3.8919x over previous
//
#include <hip/hip_runtime.h>
#include <hip/hip_bf16.h>

#define N_NODES 20000
#define N_EDGES 640000
#define HID 256
#define INDIM 128

// ---------- ws layout (bytes) ----------
#define WS_H_OFF   0u           // h bf16: 20000*256*2 = 10,240,000
#define WS_AGG_OFF 10240000u    // agg f32: 20000*256*4 = 20,480,000
#define WS_CS_OFF  30720000u    // colsum: 256*4 = 1024
#define WS_DEG_OFF 30721024u    // deg: 20000*4 = 80,000
#define WS_ROW_OFF 30801024u    // rowstart: 20001*4 = 80,004
#define WS_CUR_OFF 30881028u    // cursor: 20000*4 = 80,000
#define WS_SRC_OFF 30961028u    // srcs: 640000*4 = 2,560,000
#define WS_NEEDED  33521028u

__device__ inline unsigned short f2bf(float v) {
    union { float f; unsigned int u; } c; c.f = v;
    unsigned int lsb = (c.u >> 16) & 1u;
    c.u += 0x7fffu + lsb;                 // round-to-nearest-even
    return (unsigned short)(c.u >> 16);
}
__device__ inline float bf2f(unsigned short u) {
    union { float f; unsigned int u; } c; c.u = ((unsigned int)u) << 16;
    return c.f;
}

// ---------------------------------------------------------------------------
// Kernel 1: h = relu(x @ emb_W.T + emb_b), stored bf16.
// Lean-register version: w chunk = 4 float4 (16 VGPRs), kc loop NOT unrolled.
// acc[32] + w[4x4] + xs temps ~= 80-100 VGPRs -> no spill, good occupancy.
// xs reads are wave-uniform broadcasts (lanes differ only in W row j).
// ---------------------------------------------------------------------------
__global__ __launch_bounds__(256) void k_embed(const float* __restrict__ x,
                                               const float* __restrict__ W,
                                               const float* __restrict__ b,
                                               unsigned short* __restrict__ hbf)
{
    __shared__ float xs[32 * INDIM];   // 16 KB
    const int tid = threadIdx.x;
    const int n0  = blockIdx.x * 32;

    {
        const float4* xg = (const float4*)(x + (size_t)n0 * INDIM);
        float4* xs4 = (float4*)xs;
#pragma unroll
        for (int i = 0; i < 4; ++i) xs4[tid + i * 256] = xg[tid + i * 256];
    }
    __syncthreads();

    const int j = tid;
    const float4* wr = (const float4*)(W + (size_t)j * INDIM);   // 32 float4
    const float bias = b[j];

    float acc[32];
#pragma unroll
    for (int n = 0; n < 32; ++n) acc[n] = bias;

#pragma unroll 1
    for (int kc = 0; kc < 8; ++kc) {           // 16 floats per chunk
        const float4 w0 = wr[kc * 4 + 0];
        const float4 w1 = wr[kc * 4 + 1];
        const float4 w2 = wr[kc * 4 + 2];
        const float4 w3 = wr[kc * 4 + 3];
#pragma unroll
        for (int n = 0; n < 32; ++n) {
            const float4* xp = (const float4*)(xs + n * INDIM + kc * 16);
            float4 x0 = xp[0], x1 = xp[1], x2 = xp[2], x3 = xp[3];
            acc[n] += x0.x * w0.x + x0.y * w0.y + x0.z * w0.z + x0.w * w0.w
                    + x1.x * w1.x + x1.y * w1.y + x1.z * w1.z + x1.w * w1.w
                    + x2.x * w2.x + x2.y * w2.y + x2.z * w2.z + x2.w * w2.w
                    + x3.x * w3.x + x3.y * w3.y + x3.z * w3.z + x3.w * w3.w;
        }
    }

#pragma unroll
    for (int n = 0; n < 32; ++n) {
        float v = acc[n] > 0.f ? acc[n] : 0.f;
        hbf[(size_t)(n0 + n) * HID + j] = f2bf(v);
    }
}

// ---------------------------------------------------------------------------
// CSR build: count degrees, scan, fill src lists.
// ---------------------------------------------------------------------------
__global__ __launch_bounds__(256) void k_count(const int* __restrict__ ei,
                                               int* __restrict__ deg)
{
    const int e = blockIdx.x * 256 + threadIdx.x;
    if (e >= N_EDGES) return;
    atomicAdd(&deg[ei[e]], 1);
}

__global__ __launch_bounds__(1024) void k_scan(const int* __restrict__ deg,
                                               int* __restrict__ rowstart)
{
    __shared__ int sums[1024];
    const int t = threadIdx.x;
    const int per = 20;                     // 1024*20 = 20480 >= 20000
    const int base = t * per;

    int local[per];
    int s = 0;
#pragma unroll
    for (int i = 0; i < per; ++i) {
        int idx = base + i;
        int v = (idx < N_NODES) ? deg[idx] : 0;
        local[i] = s;
        s += v;
    }
    sums[t] = s;
    __syncthreads();

    for (int off = 1; off < 1024; off <<= 1) {
        int v = 0;
        if (t >= off) v = sums[t - off];
        __syncthreads();
        if (t >= off) sums[t] += v;
        __syncthreads();
    }

    const int pre = (t == 0) ? 0 : sums[t - 1];
#pragma unroll
    for (int i = 0; i < per; ++i) {
        int idx = base + i;
        if (idx < N_NODES) rowstart[idx] = pre + local[i];
    }
    if (t == 1023) rowstart[N_NODES] = sums[1023];
}

__global__ __launch_bounds__(256) void k_fill(const int* __restrict__ ei,
                                              const int* __restrict__ rowstart,
                                              int* __restrict__ cursor,
                                              int* __restrict__ srcs)
{
    const int e = blockIdx.x * 256 + threadIdx.x;
    if (e >= N_EDGES) return;
    const int dst = ei[e];
    const int src = ei[N_EDGES + e];
    const int pos = rowstart[dst] + atomicAdd(&cursor[dst], 1);
    srcs[pos] = src;
}

// ---------------------------------------------------------------------------
// Gather: one wave per dst node; lane holds 4 columns. No f32 atomics.
// ---------------------------------------------------------------------------
__global__ __launch_bounds__(256) void k_gather(const int* __restrict__ rowstart,
                                                const int* __restrict__ srcs,
                                                const unsigned short* __restrict__ hbf,
                                                float* __restrict__ agg)
{
    const int wid  = (blockIdx.x * 256 + threadIdx.x) >> 6;  // node id
    const int lane = threadIdx.x & 63;
    if (wid >= N_NODES) return;

    const int s0 = rowstart[wid];
    const int s1 = rowstart[wid + 1];

    float4 acc = make_float4(0.f, 0.f, 0.f, 0.f);
    const ushort4* h4 = (const ushort4*)hbf;

    int e = s0;
    for (; e + 1 < s1; e += 2) {
        int srcA = srcs[e];
        int srcB = srcs[e + 1];
        ushort4 a = h4[(size_t)srcA * 64 + lane];
        ushort4 bv = h4[(size_t)srcB * 64 + lane];
        acc.x += bf2f(a.x) + bf2f(bv.x);
        acc.y += bf2f(a.y) + bf2f(bv.y);
        acc.z += bf2f(a.z) + bf2f(bv.z);
        acc.w += bf2f(a.w) + bf2f(bv.w);
    }
    if (e < s1) {
        int srcA = srcs[e];
        ushort4 a = h4[(size_t)srcA * 64 + lane];
        acc.x += bf2f(a.x);
        acc.y += bf2f(a.y);
        acc.z += bf2f(a.z);
        acc.w += bf2f(a.w);
    }

    ((float4*)agg)[(size_t)wid * 64 + lane] = acc;
}

// ---------------------------------------------------------------------------
// Fallback scatter (atomic path) if ws too small for CSR.
// ---------------------------------------------------------------------------
__global__ __launch_bounds__(256) void k_scatter(const int* __restrict__ ei,
                                                 const unsigned short* __restrict__ hbf,
                                                 float* __restrict__ agg)
{
    const int gtid = blockIdx.x * 256 + threadIdx.x;
    const int e    = gtid >> 6;
    const int lane = threadIdx.x & 63;
    if (e >= N_EDGES) return;

    const int dst = ei[e];
    const int src = ei[N_EDGES + e];

    ushort4 hv = ((const ushort4*)hbf)[(size_t)src * 64 + lane];
    float* a = agg + (size_t)dst * HID + lane * 4;
    unsafeAtomicAdd(a + 0, bf2f(hv.x));
    unsafeAtomicAdd(a + 1, bf2f(hv.y));
    unsafeAtomicAdd(a + 2, bf2f(hv.z));
    unsafeAtomicAdd(a + 3, bf2f(hv.w));
}

// ---------------------------------------------------------------------------
// Kernel 3: h2 = relu(agg @ msg_W.T + msg_b); column-sum into colsum.
// Same lean-register structure as k_embed; h2 never materialized.
// ---------------------------------------------------------------------------
__global__ __launch_bounds__(256) void k_msg(const float* __restrict__ agg,
                                             const float* __restrict__ W,
                                             const float* __restrict__ b,
                                             float* __restrict__ colsum)
{
    __shared__ float xs[32 * HID];     // 32 KB
    const int tid = threadIdx.x;
    const int n0  = blockIdx.x * 32;

    {
        const float4* xg = (const float4*)(agg + (size_t)n0 * HID);
        float4* xs4 = (float4*)xs;
#pragma unroll
        for (int i = 0; i < 8; ++i) xs4[tid + i * 256] = xg[tid + i * 256];
    }
    __syncthreads();

    const int j = tid;
    const float4* wr = (const float4*)(W + (size_t)j * HID);    // 64 float4
    const float bias = b[j];

    float acc[32];
#pragma unroll
    for (int n = 0; n < 32; ++n) acc[n] = bias;

#pragma unroll 1
    for (int kc = 0; kc < 16; ++kc) {          // 16 floats per chunk
        const float4 w0 = wr[kc * 4 + 0];
        const float4 w1 = wr[kc * 4 + 1];
        const float4 w2 = wr[kc * 4 + 2];
        const float4 w3 = wr[kc * 4 + 3];
#pragma unroll
        for (int n = 0; n < 32; ++n) {
            const float4* xp = (const float4*)(xs + n * HID + kc * 16);
            float4 x0 = xp[0], x1 = xp[1], x2 = xp[2], x3 = xp[3];
            acc[n] += x0.x * w0.x + x0.y * w0.y + x0.z * w0.z + x0.w * w0.w
                    + x1.x * w1.x + x1.y * w1.y + x1.z * w1.z + x1.w * w1.w
                    + x2.x * w2.x + x2.y * w2.y + x2.z * w2.z + x2.w * w2.w
                    + x3.x * w3.x + x3.y * w3.y + x3.z * w3.z + x3.w * w3.w;
        }
    }

    float part = 0.f;
#pragma unroll
    for (int n = 0; n < 32; ++n) {
        float v = acc[n] > 0.f ? acc[n] : 0.f;
        part += v;
    }
    unsafeAtomicAdd(&colsum[j], part);
}

// ---------------------------------------------------------------------------
// Kernel 4: output matvecs from hmean. Unroll capped to keep regs sane.
// ---------------------------------------------------------------------------
__global__ __launch_bounds__(256) void k_out(const float* __restrict__ colsum,
                                             const float* __restrict__ W0,
                                             const float* __restrict__ b0,
                                             const float* __restrict__ W1,
                                             const float* __restrict__ b1,
                                             float* __restrict__ out)
{
    __shared__ float hm[HID];
    const int tid = threadIdx.x;
    hm[tid] = colsum[tid] * (1.0f / (float)N_NODES);
    __syncthreads();

    const int o = blockIdx.x * 256 + tid;
    const float* Wr;
    float bias;
    if (o < 8192) { Wr = W0 + (size_t)o * HID; bias = b0[o]; }
    else          { int o1 = o - 8192; Wr = W1 + (size_t)o1 * HID; bias = b1[o1]; }

    float s = bias;
    const float4* w4 = (const float4*)Wr;
    const float4* h4 = (const float4*)hm;
#pragma unroll 8
    for (int q = 0; q < 64; ++q) {
        float4 wv = w4[q];
        float4 hv = h4[q];
        s += wv.x * hv.x + wv.y * hv.y + wv.z * hv.z + wv.w * hv.w;
    }
    out[o] = s;
}

// ---------------------------------------------------------------------------
extern "C" void kernel_launch(void* const* d_in, const int* in_sizes, int n_in,
                              void* d_out, int out_size, void* d_ws, size_t ws_size,
                              hipStream_t stream)
{
    const float* x     = (const float*)d_in[0];
    const int*   ei    = (const int*)d_in[1];
    const float* emb_W = (const float*)d_in[2];
    const float* emb_b = (const float*)d_in[3];
    const float* msg_W = (const float*)d_in[4];
    const float* msg_b = (const float*)d_in[5];
    const float* W0    = (const float*)d_in[6];
    const float* b0    = (const float*)d_in[7];
    const float* W1    = (const float*)d_in[8];
    const float* b1    = (const float*)d_in[9];
    float* out = (float*)d_out;

    char* ws = (char*)d_ws;
    unsigned short* hbf = (unsigned short*)(ws + WS_H_OFF);
    float* agg    = (float*)(ws + WS_AGG_OFF);
    float* colsum = (float*)(ws + WS_CS_OFF);

    k_embed<<<N_NODES / 32, 256, 0, stream>>>(x, emb_W, emb_b, hbf);

    if (ws_size >= WS_NEEDED) {
        int* deg      = (int*)(ws + WS_DEG_OFF);
        int* rowstart = (int*)(ws + WS_ROW_OFF);
        int* cursor   = (int*)(ws + WS_CUR_OFF);
        int* srcs     = (int*)(ws + WS_SRC_OFF);

        // zero colsum + deg + rowstart + cursor in one shot
        hipMemsetAsync(ws + WS_CS_OFF, 0, WS_SRC_OFF - WS_CS_OFF, stream);

        k_count <<<(N_EDGES + 255) / 256, 256, 0, stream>>>(ei, deg);
        k_scan  <<<1, 1024, 0, stream>>>(deg, rowstart);
        k_fill  <<<(N_EDGES + 255) / 256, 256, 0, stream>>>(ei, rowstart, cursor, srcs);
        k_gather<<<(N_NODES * 64 + 255) / 256, 256, 0, stream>>>(rowstart, srcs, hbf, agg);
    } else {
        // fallback: atomic scatter
        hipMemsetAsync(agg, 0, (size_t)N_NODES * HID * 4 + HID * 4, stream);
        k_scatter<<<N_EDGES / 4, 256, 0, stream>>>(ei, hbf, agg);
    }

    k_msg<<<N_NODES / 32, 256, 0, stream>>>(agg, msg_W, msg_b, colsum);
    k_out<<<(8192 + 2048) / 256, 256, 0, stream>>>(colsum, W0, b0, W1, b1, out);
}

// Round 4
// 177.286 us; speedup vs baseline: 18.4036x; 1.8362x over previous
//
#include <hip/hip_runtime.h>
#include <hip/hip_bf16.h>

#define N_NODES 20000
#define N_EDGES 640000
#define HID 256
#define INDIM 128

// ---------- ws layout (bytes) ----------
#define WS_H_OFF    0u          // h bf16: 20000*256*2 = 10,240,000
#define WS_AGG_OFF  10240000u   // agg bf16: 20000*256*2 = 10,240,000
#define WS_XBF_OFF  20480000u   // x bf16: 20000*128*2 = 5,120,000
#define WS_EW_OFF   25600000u   // emb_W bf16: 256*128*2 = 65,536
#define WS_MW_OFF   25665536u   // msg_W bf16: 256*256*2 = 131,072
#define WS_CS_OFF   25796608u   // colsum f32: 1024
#define WS_DEG_OFF  25797632u   // deg: 80,000
#define WS_ROW_OFF  25877632u   // rowstart: 80,004 (+124 pad)
#define WS_CUR_OFF  25957760u   // cursor: 80,000
#define WS_SRC_OFF  26037760u   // srcs: 2,560,000
#define WS_NEEDED   28597760u

#define X_ELEMS  (N_NODES * INDIM)          // 2,560,000
#define EW_ELEMS (HID * INDIM)              // 32,768
#define MW_ELEMS (HID * HID)                // 65,536

typedef __attribute__((ext_vector_type(8))) short bf16x8;
typedef __attribute__((ext_vector_type(4))) float f32x4;

__device__ inline unsigned short f2bf(float v) {
    union { float f; unsigned int u; } c; c.f = v;
    unsigned int lsb = (c.u >> 16) & 1u;
    c.u += 0x7fffu + lsb;                 // round-to-nearest-even
    return (unsigned short)(c.u >> 16);
}
__device__ inline float bf2f(unsigned short u) {
    union { float f; unsigned int u; } c; c.u = ((unsigned int)u) << 16;
    return c.f;
}

// ---------------------------------------------------------------------------
// Convert x, emb_W, msg_W to bf16 (one flat kernel, 8 elems/thread).
// ---------------------------------------------------------------------------
__global__ __launch_bounds__(256) void k_convert(const float* __restrict__ x,
                                                 const float* __restrict__ eW,
                                                 const float* __restrict__ mW,
                                                 unsigned short* __restrict__ xbf,
                                                 unsigned short* __restrict__ eWbf,
                                                 unsigned short* __restrict__ mWbf)
{
    const int t = blockIdx.x * 256 + threadIdx.x;
    const int i8 = t * 8;
    const float* src;
    unsigned short* dst;
    int off;
    if (i8 < X_ELEMS)                 { src = x;  dst = xbf;  off = i8; }
    else if (i8 < X_ELEMS + EW_ELEMS) { src = eW; dst = eWbf; off = i8 - X_ELEMS; }
    else                              { src = mW; dst = mWbf; off = i8 - X_ELEMS - EW_ELEMS; }

    float4 a = *(const float4*)(src + off);
    float4 b = *(const float4*)(src + off + 4);
    unsigned short o[8] = { f2bf(a.x), f2bf(a.y), f2bf(a.z), f2bf(a.w),
                            f2bf(b.x), f2bf(b.y), f2bf(b.z), f2bf(b.w) };
    *(bf16x8*)(dst + off) = *(bf16x8*)o;
}

// ---------------------------------------------------------------------------
// MFMA embed: h = relu(x @ emb_W.T + emb_b), bf16 in/out.
// Block = 64 nodes x 256 cols, 4 waves; wave w owns cols [w*64, w*64+64).
// A/B frags read directly from global (W L2-resident, x row-segments 64B).
// ---------------------------------------------------------------------------
__global__ __launch_bounds__(256) void k_embed_mfma(const unsigned short* __restrict__ xbf,
                                                    const unsigned short* __restrict__ Wbf,
                                                    const float* __restrict__ b,
                                                    unsigned short* __restrict__ hbf)
{
    const int tid  = threadIdx.x;
    const int wave = tid >> 6;
    const int lane = tid & 63;
    const int lr   = lane & 15;
    const int lq   = lane >> 4;
    const int n0   = blockIdx.x * 64;
    const int colbase = wave * 64;

    f32x4 acc[4][4] = {};

#pragma unroll
    for (int kk = 0; kk < INDIM; kk += 32) {
        bf16x8 a[4], bb[4];
#pragma unroll
        for (int g = 0; g < 4; ++g)
            a[g] = *(const bf16x8*)(xbf + (size_t)(n0 + g * 16 + lr) * INDIM + kk + lq * 8);
#pragma unroll
        for (int c = 0; c < 4; ++c)
            bb[c] = *(const bf16x8*)(Wbf + (size_t)(colbase + c * 16 + lr) * INDIM + kk + lq * 8);
#pragma unroll
        for (int g = 0; g < 4; ++g)
#pragma unroll
            for (int c = 0; c < 4; ++c)
                acc[g][c] = __builtin_amdgcn_mfma_f32_16x16x32_bf16(a[g], bb[c], acc[g][c], 0, 0, 0);
    }

#pragma unroll
    for (int c = 0; c < 4; ++c) {
        const int j = colbase + c * 16 + lr;
        const float bias = b[j];
#pragma unroll
        for (int g = 0; g < 4; ++g) {
            const int nbase = n0 + g * 16 + lq * 4;
#pragma unroll
            for (int r = 0; r < 4; ++r) {
                const int n = nbase + r;
                if (n < N_NODES) {
                    float v = acc[g][c][r] + bias;
                    v = v > 0.f ? v : 0.f;
                    hbf[(size_t)n * HID + j] = f2bf(v);
                }
            }
        }
    }
}

// ---------------------------------------------------------------------------
// CSR build: count degrees, scan, fill src lists.
// ---------------------------------------------------------------------------
__global__ __launch_bounds__(256) void k_count(const int* __restrict__ ei,
                                               int* __restrict__ deg)
{
    const int e = blockIdx.x * 256 + threadIdx.x;
    if (e >= N_EDGES) return;
    atomicAdd(&deg[ei[e]], 1);
}

__global__ __launch_bounds__(1024) void k_scan(const int* __restrict__ deg,
                                               int* __restrict__ rowstart)
{
    __shared__ int sums[1024];
    const int t = threadIdx.x;
    const int per = 20;                     // 1024*20 = 20480 >= 20000
    const int base = t * per;

    int local[per];
    int s = 0;
#pragma unroll
    for (int i = 0; i < per; ++i) {
        int idx = base + i;
        int v = (idx < N_NODES) ? deg[idx] : 0;
        local[i] = s;
        s += v;
    }
    sums[t] = s;
    __syncthreads();

    for (int off = 1; off < 1024; off <<= 1) {
        int v = 0;
        if (t >= off) v = sums[t - off];
        __syncthreads();
        if (t >= off) sums[t] += v;
        __syncthreads();
    }

    const int pre = (t == 0) ? 0 : sums[t - 1];
#pragma unroll
    for (int i = 0; i < per; ++i) {
        int idx = base + i;
        if (idx < N_NODES) rowstart[idx] = pre + local[i];
    }
    if (t == 1023) rowstart[N_NODES] = sums[1023];
}

__global__ __launch_bounds__(256) void k_fill(const int* __restrict__ ei,
                                              const int* __restrict__ rowstart,
                                              int* __restrict__ cursor,
                                              int* __restrict__ srcs)
{
    const int e = blockIdx.x * 256 + threadIdx.x;
    if (e >= N_EDGES) return;
    const int dst = ei[e];
    const int src = ei[N_EDGES + e];
    const int pos = rowstart[dst] + atomicAdd(&cursor[dst], 1);
    srcs[pos] = src;
}

// ---------------------------------------------------------------------------
// Gather: one wave per dst node; lane holds 4 columns; f32 accumulate,
// bf16 store. Unroll 4 for load-latency hiding.
// ---------------------------------------------------------------------------
__global__ __launch_bounds__(256) void k_gather(const int* __restrict__ rowstart,
                                                const int* __restrict__ srcs,
                                                const unsigned short* __restrict__ hbf,
                                                unsigned short* __restrict__ aggbf)
{
    const int wid  = (blockIdx.x * 256 + threadIdx.x) >> 6;  // node id
    const int lane = threadIdx.x & 63;
    if (wid >= N_NODES) return;

    const int s0 = rowstart[wid];
    const int s1 = rowstart[wid + 1];

    float4 acc = make_float4(0.f, 0.f, 0.f, 0.f);
    const ushort4* h4 = (const ushort4*)hbf;

    int e = s0;
    for (; e + 3 < s1; e += 4) {
        int sA = srcs[e], sB = srcs[e + 1], sC = srcs[e + 2], sD = srcs[e + 3];
        ushort4 a = h4[(size_t)sA * 64 + lane];
        ushort4 b = h4[(size_t)sB * 64 + lane];
        ushort4 c = h4[(size_t)sC * 64 + lane];
        ushort4 d = h4[(size_t)sD * 64 + lane];
        acc.x += (bf2f(a.x) + bf2f(b.x)) + (bf2f(c.x) + bf2f(d.x));
        acc.y += (bf2f(a.y) + bf2f(b.y)) + (bf2f(c.y) + bf2f(d.y));
        acc.z += (bf2f(a.z) + bf2f(b.z)) + (bf2f(c.z) + bf2f(d.z));
        acc.w += (bf2f(a.w) + bf2f(b.w)) + (bf2f(c.w) + bf2f(d.w));
    }
    for (; e < s1; ++e) {
        ushort4 a = h4[(size_t)srcs[e] * 64 + lane];
        acc.x += bf2f(a.x);
        acc.y += bf2f(a.y);
        acc.z += bf2f(a.z);
        acc.w += bf2f(a.w);
    }

    ushort4 o;
    o.x = f2bf(acc.x); o.y = f2bf(acc.y); o.z = f2bf(acc.z); o.w = f2bf(acc.w);
    ((ushort4*)aggbf)[(size_t)wid * 64 + lane] = o;
}

// ---------------------------------------------------------------------------
// MFMA msg layer: h2 = relu(agg @ msg_W.T + msg_b), column-summed into
// colsum without materializing h2. Same tile as k_embed_mfma, K=256.
// ---------------------------------------------------------------------------
__global__ __launch_bounds__(256) void k_msg_mfma(const unsigned short* __restrict__ aggbf,
                                                  const unsigned short* __restrict__ Wbf,
                                                  const float* __restrict__ b,
                                                  float* __restrict__ colsum)
{
    const int tid  = threadIdx.x;
    const int wave = tid >> 6;
    const int lane = tid & 63;
    const int lr   = lane & 15;
    const int lq   = lane >> 4;
    const int n0   = blockIdx.x * 64;
    const int colbase = wave * 64;

    f32x4 acc[4][4] = {};

#pragma unroll
    for (int kk = 0; kk < HID; kk += 32) {
        bf16x8 a[4], bb[4];
#pragma unroll
        for (int g = 0; g < 4; ++g)
            a[g] = *(const bf16x8*)(aggbf + (size_t)(n0 + g * 16 + lr) * HID + kk + lq * 8);
#pragma unroll
        for (int c = 0; c < 4; ++c)
            bb[c] = *(const bf16x8*)(Wbf + (size_t)(colbase + c * 16 + lr) * HID + kk + lq * 8);
#pragma unroll
        for (int g = 0; g < 4; ++g)
#pragma unroll
            for (int c = 0; c < 4; ++c)
                acc[g][c] = __builtin_amdgcn_mfma_f32_16x16x32_bf16(a[g], bb[c], acc[g][c], 0, 0, 0);
    }

#pragma unroll
    for (int c = 0; c < 4; ++c) {
        const int j = colbase + c * 16 + lr;
        const float bias = b[j];
        float part = 0.f;
#pragma unroll
        for (int g = 0; g < 4; ++g) {
            if (n0 + g * 16 < N_NODES) {      // tail is 16-row aligned: exact
#pragma unroll
                for (int r = 0; r < 4; ++r) {
                    float v = acc[g][c][r] + bias;
                    part += v > 0.f ? v : 0.f;
                }
            }
        }
        part += __shfl_xor(part, 16);
        part += __shfl_xor(part, 32);
        if (lane < 16) unsafeAtomicAdd(&colsum[j], part);
    }
}

// ---------------------------------------------------------------------------
// Output matvecs from hmean = colsum / N.
// ---------------------------------------------------------------------------
__global__ __launch_bounds__(256) void k_out(const float* __restrict__ colsum,
                                             const float* __restrict__ W0,
                                             const float* __restrict__ b0,
                                             const float* __restrict__ W1,
                                             const float* __restrict__ b1,
                                             float* __restrict__ out)
{
    __shared__ float hm[HID];
    const int tid = threadIdx.x;
    hm[tid] = colsum[tid] * (1.0f / (float)N_NODES);
    __syncthreads();

    const int o = blockIdx.x * 256 + tid;
    const float* Wr;
    float bias;
    if (o < 8192) { Wr = W0 + (size_t)o * HID; bias = b0[o]; }
    else          { int o1 = o - 8192; Wr = W1 + (size_t)o1 * HID; bias = b1[o1]; }

    float s = bias;
    const float4* w4 = (const float4*)Wr;
    const float4* h4 = (const float4*)hm;
#pragma unroll 8
    for (int q = 0; q < 64; ++q) {
        float4 wv = w4[q];
        float4 hv = h4[q];
        s += wv.x * hv.x + wv.y * hv.y + wv.z * hv.z + wv.w * hv.w;
    }
    out[o] = s;
}

// ---------------------------------------------------------------------------
extern "C" void kernel_launch(void* const* d_in, const int* in_sizes, int n_in,
                              void* d_out, int out_size, void* d_ws, size_t ws_size,
                              hipStream_t stream)
{
    const float* x     = (const float*)d_in[0];
    const int*   ei    = (const int*)d_in[1];
    const float* emb_W = (const float*)d_in[2];
    const float* emb_b = (const float*)d_in[3];
    const float* msg_W = (const float*)d_in[4];
    const float* msg_b = (const float*)d_in[5];
    const float* W0    = (const float*)d_in[6];
    const float* b0    = (const float*)d_in[7];
    const float* W1    = (const float*)d_in[8];
    const float* b1    = (const float*)d_in[9];
    float* out = (float*)d_out;

    char* ws = (char*)d_ws;
    unsigned short* hbf   = (unsigned short*)(ws + WS_H_OFF);
    unsigned short* aggbf = (unsigned short*)(ws + WS_AGG_OFF);
    unsigned short* xbf   = (unsigned short*)(ws + WS_XBF_OFF);
    unsigned short* eWbf  = (unsigned short*)(ws + WS_EW_OFF);
    unsigned short* mWbf  = (unsigned short*)(ws + WS_MW_OFF);
    float* colsum = (float*)(ws + WS_CS_OFF);
    int* deg      = (int*)(ws + WS_DEG_OFF);
    int* rowstart = (int*)(ws + WS_ROW_OFF);
    int* cursor   = (int*)(ws + WS_CUR_OFF);
    int* srcs     = (int*)(ws + WS_SRC_OFF);

    // zero colsum + deg + rowstart + cursor (contiguous)
    hipMemsetAsync(ws + WS_CS_OFF, 0, WS_SRC_OFF - WS_CS_OFF, stream);

    // bf16 conversions: x, emb_W, msg_W
    {
        const int total8 = (X_ELEMS + EW_ELEMS + MW_ELEMS) / 8;     // 332,288
        k_convert<<<total8 / 256, 256, 0, stream>>>(x, emb_W, msg_W, xbf, eWbf, mWbf);
    }

    k_embed_mfma<<<(N_NODES + 63) / 64, 256, 0, stream>>>(xbf, eWbf, emb_b, hbf);

    k_count <<<(N_EDGES + 255) / 256, 256, 0, stream>>>(ei, deg);
    k_scan  <<<1, 1024, 0, stream>>>(deg, rowstart);
    k_fill  <<<(N_EDGES + 255) / 256, 256, 0, stream>>>(ei, rowstart, cursor, srcs);
    k_gather<<<(N_NODES * 64 + 255) / 256, 256, 0, stream>>>(rowstart, srcs, hbf, aggbf);

    k_msg_mfma<<<(N_NODES + 63) / 64, 256, 0, stream>>>(aggbf, mWbf, msg_b, colsum);
    k_out<<<(8192 + 2048) / 256, 256, 0, stream>>>(colsum, W0, b0, W1, b1, out);
}

// Round 5
// 173.462 us; speedup vs baseline: 18.8093x; 1.0220x over previous
//
#include <hip/hip_runtime.h>
#include <hip/hip_bf16.h>

#define N_NODES 20000
#define N_EDGES 640000
#define HID 256
#define INDIM 128

// ---------- ws layout (bytes) ----------
#define WS_H_OFF    0u          // h bf16: 20000*256*2 = 10,240,000
#define WS_AGG_OFF  10240000u   // agg bf16: 20000*256*2 = 10,240,000
#define WS_XBF_OFF  20480000u   // x bf16: 20000*128*2 = 5,120,000
#define WS_EW_OFF   25600000u   // emb_W bf16: 256*128*2 = 65,536
#define WS_MW_OFF   25665536u   // msg_W bf16: 256*256*2 = 131,072
#define WS_CS_OFF   25796608u   // colsum f32: 1024   (zeroed; contiguous with deg)
#define WS_DEG_OFF  25797632u   // deg: 80,000        (zeroed; doubles as fill cursor)
#define WS_ROW_OFF  25877632u   // rowstart: 80,004 (+124 pad)
#define WS_SRC_OFF  25957760u   // srcs: 2,560,000
#define WS_NEEDED   28517760u

#define X_ELEMS  (N_NODES * INDIM)          // 2,560,000
#define EW_ELEMS (HID * INDIM)              // 32,768
#define MW_ELEMS (HID * HID)                // 65,536
#define CONV_BLOCKS ((X_ELEMS + EW_ELEMS + MW_ELEMS) / 8 / 256)   // 1298 exact
#define ZERO_BYTES  (1024 + 80000)          // colsum + deg, contiguous
#define ZERO_F4     (ZERO_BYTES / 16)       // 5064 exact
#define ZERO_BLOCKS ((ZERO_F4 + 255) / 256) // 20

typedef __attribute__((ext_vector_type(8))) short bf16x8;
typedef __attribute__((ext_vector_type(4))) float f32x4;

__device__ inline unsigned short f2bf(float v) {
    union { float f; unsigned int u; } c; c.f = v;
    unsigned int lsb = (c.u >> 16) & 1u;
    c.u += 0x7fffu + lsb;                 // round-to-nearest-even
    return (unsigned short)(c.u >> 16);
}
__device__ inline float bf2f(unsigned short u) {
    union { float f; unsigned int u; } c; c.u = ((unsigned int)u) << 16;
    return c.f;
}

// ---------------------------------------------------------------------------
// Convert x, emb_W, msg_W to bf16; tail blocks zero colsum+deg (81 KB).
// Replaces hipMemsetAsync (rocclr fill kernel was 43 us for 241 KB).
// ---------------------------------------------------------------------------
__global__ __launch_bounds__(256) void k_convert(const float* __restrict__ x,
                                                 const float* __restrict__ eW,
                                                 const float* __restrict__ mW,
                                                 unsigned short* __restrict__ xbf,
                                                 unsigned short* __restrict__ eWbf,
                                                 unsigned short* __restrict__ mWbf,
                                                 float4* __restrict__ zbase)
{
    if (blockIdx.x >= CONV_BLOCKS) {
        const int zi = (blockIdx.x - CONV_BLOCKS) * 256 + threadIdx.x;
        if (zi < ZERO_F4) zbase[zi] = make_float4(0.f, 0.f, 0.f, 0.f);
        return;
    }
    const int t = blockIdx.x * 256 + threadIdx.x;
    const int i8 = t * 8;
    const float* src;
    unsigned short* dst;
    int off;
    if (i8 < X_ELEMS)                 { src = x;  dst = xbf;  off = i8; }
    else if (i8 < X_ELEMS + EW_ELEMS) { src = eW; dst = eWbf; off = i8 - X_ELEMS; }
    else                              { src = mW; dst = mWbf; off = i8 - X_ELEMS - EW_ELEMS; }

    float4 a = *(const float4*)(src + off);
    float4 b = *(const float4*)(src + off + 4);
    unsigned short o[8] = { f2bf(a.x), f2bf(a.y), f2bf(a.z), f2bf(a.w),
                            f2bf(b.x), f2bf(b.y), f2bf(b.z), f2bf(b.w) };
    *(bf16x8*)(dst + off) = *(bf16x8*)o;
}

// ---------------------------------------------------------------------------
// MFMA embed: h = relu(x @ emb_W.T + emb_b), bf16 in/out.
// Block = 64 nodes x 256 cols, 4 waves; wave w owns cols [w*64, w*64+64).
// ---------------------------------------------------------------------------
__global__ __launch_bounds__(256) void k_embed_mfma(const unsigned short* __restrict__ xbf,
                                                    const unsigned short* __restrict__ Wbf,
                                                    const float* __restrict__ b,
                                                    unsigned short* __restrict__ hbf)
{
    const int tid  = threadIdx.x;
    const int wave = tid >> 6;
    const int lane = tid & 63;
    const int lr   = lane & 15;
    const int lq   = lane >> 4;
    const int n0   = blockIdx.x * 64;
    const int colbase = wave * 64;

    f32x4 acc[4][4] = {};

#pragma unroll
    for (int kk = 0; kk < INDIM; kk += 32) {
        bf16x8 a[4], bb[4];
#pragma unroll
        for (int g = 0; g < 4; ++g)
            a[g] = *(const bf16x8*)(xbf + (size_t)(n0 + g * 16 + lr) * INDIM + kk + lq * 8);
#pragma unroll
        for (int c = 0; c < 4; ++c)
            bb[c] = *(const bf16x8*)(Wbf + (size_t)(colbase + c * 16 + lr) * INDIM + kk + lq * 8);
#pragma unroll
        for (int g = 0; g < 4; ++g)
#pragma unroll
            for (int c = 0; c < 4; ++c)
                acc[g][c] = __builtin_amdgcn_mfma_f32_16x16x32_bf16(a[g], bb[c], acc[g][c], 0, 0, 0);
    }

#pragma unroll
    for (int c = 0; c < 4; ++c) {
        const int j = colbase + c * 16 + lr;
        const float bias = b[j];
#pragma unroll
        for (int g = 0; g < 4; ++g) {
            const int nbase = n0 + g * 16 + lq * 4;
#pragma unroll
            for (int r = 0; r < 4; ++r) {
                const int n = nbase + r;
                if (n < N_NODES) {
                    float v = acc[g][c][r] + bias;
                    v = v > 0.f ? v : 0.f;
                    hbf[(size_t)n * HID + j] = f2bf(v);
                }
            }
        }
    }
}

// ---------------------------------------------------------------------------
// CSR build: count degrees, scan, fill src lists (deg doubles as cursor).
// ---------------------------------------------------------------------------
__global__ __launch_bounds__(256) void k_count(const int* __restrict__ ei,
                                               int* __restrict__ deg)
{
    const int e = blockIdx.x * 256 + threadIdx.x;
    if (e >= N_EDGES) return;
    atomicAdd(&deg[ei[e]], 1);
}

__global__ __launch_bounds__(1024) void k_scan(const int* __restrict__ deg,
                                               int* __restrict__ rowstart)
{
    __shared__ int sums[1024];
    const int t = threadIdx.x;
    const int per = 20;                     // 1024*20 = 20480 >= 20000
    const int base = t * per;

    int local[per];
    int s = 0;
#pragma unroll
    for (int i = 0; i < per; ++i) {
        int idx = base + i;
        int v = (idx < N_NODES) ? deg[idx] : 0;
        local[i] = s;
        s += v;
    }
    sums[t] = s;
    __syncthreads();

    for (int off = 1; off < 1024; off <<= 1) {
        int v = 0;
        if (t >= off) v = sums[t - off];
        __syncthreads();
        if (t >= off) sums[t] += v;
        __syncthreads();
    }

    const int pre = (t == 0) ? 0 : sums[t - 1];
#pragma unroll
    for (int i = 0; i < per; ++i) {
        int idx = base + i;
        if (idx < N_NODES) rowstart[idx] = pre + local[i];
    }
    if (t == 1023) rowstart[N_NODES] = sums[1023];
}

// deg[dst] still holds the count; consume it as a countdown cursor.
__global__ __launch_bounds__(256) void k_fill(const int* __restrict__ ei,
                                              const int* __restrict__ rowstart,
                                              int* __restrict__ deg,
                                              int* __restrict__ srcs)
{
    const int e = blockIdx.x * 256 + threadIdx.x;
    if (e >= N_EDGES) return;
    const int dst = ei[e];
    const int src = ei[N_EDGES + e];
    const int pos = rowstart[dst] + atomicSub(&deg[dst], 1) - 1;
    srcs[pos] = src;
}

// ---------------------------------------------------------------------------
// Gather: one wave per dst node; lane holds 4 columns; f32 accumulate,
// bf16 store.
// ---------------------------------------------------------------------------
__global__ __launch_bounds__(256) void k_gather(const int* __restrict__ rowstart,
                                                const int* __restrict__ srcs,
                                                const unsigned short* __restrict__ hbf,
                                                unsigned short* __restrict__ aggbf)
{
    const int wid  = (blockIdx.x * 256 + threadIdx.x) >> 6;  // node id
    const int lane = threadIdx.x & 63;
    if (wid >= N_NODES) return;

    const int s0 = rowstart[wid];
    const int s1 = rowstart[wid + 1];

    float4 acc = make_float4(0.f, 0.f, 0.f, 0.f);
    const ushort4* h4 = (const ushort4*)hbf;

    int e = s0;
    for (; e + 3 < s1; e += 4) {
        int sA = srcs[e], sB = srcs[e + 1], sC = srcs[e + 2], sD = srcs[e + 3];
        ushort4 a = h4[(size_t)sA * 64 + lane];
        ushort4 b = h4[(size_t)sB * 64 + lane];
        ushort4 c = h4[(size_t)sC * 64 + lane];
        ushort4 d = h4[(size_t)sD * 64 + lane];
        acc.x += (bf2f(a.x) + bf2f(b.x)) + (bf2f(c.x) + bf2f(d.x));
        acc.y += (bf2f(a.y) + bf2f(b.y)) + (bf2f(c.y) + bf2f(d.y));
        acc.z += (bf2f(a.z) + bf2f(b.z)) + (bf2f(c.z) + bf2f(d.z));
        acc.w += (bf2f(a.w) + bf2f(b.w)) + (bf2f(c.w) + bf2f(d.w));
    }
    for (; e < s1; ++e) {
        ushort4 a = h4[(size_t)srcs[e] * 64 + lane];
        acc.x += bf2f(a.x);
        acc.y += bf2f(a.y);
        acc.z += bf2f(a.z);
        acc.w += bf2f(a.w);
    }

    ushort4 o;
    o.x = f2bf(acc.x); o.y = f2bf(acc.y); o.z = f2bf(acc.z); o.w = f2bf(acc.w);
    ((ushort4*)aggbf)[(size_t)wid * 64 + lane] = o;
}

// ---------------------------------------------------------------------------
// MFMA msg layer: h2 = relu(agg @ msg_W.T + msg_b), column-summed into
// colsum without materializing h2.
// ---------------------------------------------------------------------------
__global__ __launch_bounds__(256) void k_msg_mfma(const unsigned short* __restrict__ aggbf,
                                                  const unsigned short* __restrict__ Wbf,
                                                  const float* __restrict__ b,
                                                  float* __restrict__ colsum)
{
    const int tid  = threadIdx.x;
    const int wave = tid >> 6;
    const int lane = tid & 63;
    const int lr   = lane & 15;
    const int lq   = lane >> 4;
    const int n0   = blockIdx.x * 64;
    const int colbase = wave * 64;

    f32x4 acc[4][4] = {};

#pragma unroll
    for (int kk = 0; kk < HID; kk += 32) {
        bf16x8 a[4], bb[4];
#pragma unroll
        for (int g = 0; g < 4; ++g)
            a[g] = *(const bf16x8*)(aggbf + (size_t)(n0 + g * 16 + lr) * HID + kk + lq * 8);
#pragma unroll
        for (int c = 0; c < 4; ++c)
            bb[c] = *(const bf16x8*)(Wbf + (size_t)(colbase + c * 16 + lr) * HID + kk + lq * 8);
#pragma unroll
        for (int g = 0; g < 4; ++g)
#pragma unroll
            for (int c = 0; c < 4; ++c)
                acc[g][c] = __builtin_amdgcn_mfma_f32_16x16x32_bf16(a[g], bb[c], acc[g][c], 0, 0, 0);
    }

#pragma unroll
    for (int c = 0; c < 4; ++c) {
        const int j = colbase + c * 16 + lr;
        const float bias = b[j];
        float part = 0.f;
#pragma unroll
        for (int g = 0; g < 4; ++g) {
            if (n0 + g * 16 < N_NODES) {      // tail blocks: drop garbage rows
#pragma unroll
                for (int r = 0; r < 4; ++r) {
                    float v = acc[g][c][r] + bias;
                    part += v > 0.f ? v : 0.f;
                }
            }
        }
        part += __shfl_xor(part, 16);
        part += __shfl_xor(part, 32);
        if (lane < 16) unsafeAtomicAdd(&colsum[j], part);
    }
}

// ---------------------------------------------------------------------------
// Output matvecs from hmean = colsum / N.
// ---------------------------------------------------------------------------
__global__ __launch_bounds__(256) void k_out(const float* __restrict__ colsum,
                                             const float* __restrict__ W0,
                                             const float* __restrict__ b0,
                                             const float* __restrict__ W1,
                                             const float* __restrict__ b1,
                                             float* __restrict__ out)
{
    __shared__ float hm[HID];
    const int tid = threadIdx.x;
    hm[tid] = colsum[tid] * (1.0f / (float)N_NODES);
    __syncthreads();

    const int o = blockIdx.x * 256 + tid;
    const float* Wr;
    float bias;
    if (o < 8192) { Wr = W0 + (size_t)o * HID; bias = b0[o]; }
    else          { int o1 = o - 8192; Wr = W1 + (size_t)o1 * HID; bias = b1[o1]; }

    float s = bias;
    const float4* w4 = (const float4*)Wr;
    const float4* h4 = (const float4*)hm;
#pragma unroll 8
    for (int q = 0; q < 64; ++q) {
        float4 wv = w4[q];
        float4 hv = h4[q];
        s += wv.x * hv.x + wv.y * hv.y + wv.z * hv.z + wv.w * hv.w;
    }
    out[o] = s;
}

// ---------------------------------------------------------------------------
extern "C" void kernel_launch(void* const* d_in, const int* in_sizes, int n_in,
                              void* d_out, int out_size, void* d_ws, size_t ws_size,
                              hipStream_t stream)
{
    const float* x     = (const float*)d_in[0];
    const int*   ei    = (const int*)d_in[1];
    const float* emb_W = (const float*)d_in[2];
    const float* emb_b = (const float*)d_in[3];
    const float* msg_W = (const float*)d_in[4];
    const float* msg_b = (const float*)d_in[5];
    const float* W0    = (const float*)d_in[6];
    const float* b0    = (const float*)d_in[7];
    const float* W1    = (const float*)d_in[8];
    const float* b1    = (const float*)d_in[9];
    float* out = (float*)d_out;

    char* ws = (char*)d_ws;
    unsigned short* hbf   = (unsigned short*)(ws + WS_H_OFF);
    unsigned short* aggbf = (unsigned short*)(ws + WS_AGG_OFF);
    unsigned short* xbf   = (unsigned short*)(ws + WS_XBF_OFF);
    unsigned short* eWbf  = (unsigned short*)(ws + WS_EW_OFF);
    unsigned short* mWbf  = (unsigned short*)(ws + WS_MW_OFF);
    float* colsum = (float*)(ws + WS_CS_OFF);
    int* deg      = (int*)(ws + WS_DEG_OFF);
    int* rowstart = (int*)(ws + WS_ROW_OFF);
    int* srcs     = (int*)(ws + WS_SRC_OFF);

    // convert to bf16 + zero colsum/deg, one launch
    k_convert<<<CONV_BLOCKS + ZERO_BLOCKS, 256, 0, stream>>>(
        x, emb_W, msg_W, xbf, eWbf, mWbf, (float4*)(ws + WS_CS_OFF));

    k_embed_mfma<<<(N_NODES + 63) / 64, 256, 0, stream>>>(xbf, eWbf, emb_b, hbf);

    k_count <<<(N_EDGES + 255) / 256, 256, 0, stream>>>(ei, deg);
    k_scan  <<<1, 1024, 0, stream>>>(deg, rowstart);
    k_fill  <<<(N_EDGES + 255) / 256, 256, 0, stream>>>(ei, rowstart, deg, srcs);
    k_gather<<<(N_NODES * 64 + 255) / 256, 256, 0, stream>>>(rowstart, srcs, hbf, aggbf);

    k_msg_mfma<<<(N_NODES + 63) / 64, 256, 0, stream>>>(aggbf, mWbf, msg_b, colsum);
    k_out<<<(8192 + 2048) / 256, 256, 0, stream>>>(colsum, W0, b0, W1, b1, out);
}